// Round 3
// baseline (181.125 us; speedup 1.0000x reference)
//
#include <hip/hip_runtime.h>

// Corr2Cost: out[b,c,k,h,w] = corr[b,c,d,h,w] lerped along d at
// pos = (is_ux ? w : h) + (k - maxdisp), zero-padded outside [0, D-1].
// Harness shapes: corr (8,2,128,96,128) f32, maxdisp=50 -> K=101, is_ux=1.
//
// R3: persistent blocks, double-buffered LDS pipeline (T14 issue-early /
// write-late). Each block owns 6 consecutive (b,c,h,w-half) tiles. Per tile:
// issue next tile's 4 float4 loads into regs, compute current tile from LDS
// (conflict-free 65-stride diagonal reads, 256 B contiguous stores at
// wave-uniform k), ds_write the regs into the other buffer, one barrier.
// HBM latency hides under the previous tile's compute.

#define B_ 8
#define C_ 2
#define D_ 128
#define H_ 96
#define W_ 128
#define WT 64                       // w-half per tile
#define NHALF (W_ / WT)             // 2
#define NTILES (B_ * C_ * H_ * NHALF)  // 3072
#define NT 512
#define TPB 6                       // tiles per block
#define NBLK (NTILES / TPB)         // 512 blocks -> exactly 2 per CU

__global__ __launch_bounds__(NT, 4) void corr2cost_kernel(
    const float* __restrict__ corr,
    const int* __restrict__ maxdisp_p,
    const int* __restrict__ isux_p,
    float* __restrict__ out) {
  __shared__ float lds[2][D_ * WT];  // 2 x 32 KB

  const int t     = threadIdx.x;
  const int m     = *maxdisp_p;
  const int is_ux = *isux_p;
  const int K     = 2 * m + 1;
  const int HW    = H_ * W_;

  const int r0 = t >> 4;            // staging: 32 rows per j-pass
  const int c4 = (t & 15) * 4;      // staging col (float4)
  const int T0 = blockIdx.x * TPB;  // first tile of this block

  float4 pf[4];

  // ---- prologue: stage tile T0 into lds[0] ----
  {
    const int T    = T0;
    const int half = T & (NHALF - 1);
    const int sl   = T / NHALF;
    const int h    = sl % H_;
    const int bc   = sl / H_;
    const float* src =
        corr + (size_t)bc * D_ * HW + (size_t)h * W_ + half * WT + c4;
#pragma unroll
    for (int j = 0; j < 4; ++j)
      pf[j] = *reinterpret_cast<const float4*>(src + (size_t)(j * 32 + r0) * HW);
#pragma unroll
    for (int j = 0; j < 4; ++j)
      *reinterpret_cast<float4*>(&lds[0][(j * 32 + r0) * WT + c4]) = pf[j];
  }
  __syncthreads();

  for (int i = 0; i < TPB; ++i) {
    const int cur = i & 1;

    // (1) issue-early: global loads for tile i+1 into registers
    if (i + 1 < TPB) {
      const int T    = T0 + i + 1;
      const int half = T & (NHALF - 1);
      const int sl   = T / NHALF;
      const int h    = sl % H_;
      const int bc   = sl / H_;
      const float* src =
          corr + (size_t)bc * D_ * HW + (size_t)h * W_ + half * WT + c4;
#pragma unroll
      for (int j = 0; j < 4; ++j)
        pf[j] = *reinterpret_cast<const float4*>(src + (size_t)(j * 32 + r0) * HW);
    }

    // (2) compute tile i from lds[cur]
    {
      const int T    = T0 + i;
      const int half = T & (NHALF - 1);
      const int sl   = T / NHALF;
      const int h    = sl % H_;
      const int bc   = sl / H_;
      const int wi   = t & (WT - 1);
      const int kg   = t >> 6;      // == wave id, wave-uniform k phase
      const int w    = half * WT + wi;
      const int base = is_ux ? w : h;
      const float* L = lds[cur];
      float* dst = out + (size_t)bc * K * HW + (size_t)h * W_ + w;

      for (int k = kg; k < K; k += NT / WT) {
        const float posf = (float)(base + k - m);  // linspace step == 1.0
        const float i0f  = floorf(posf);
        const float w1   = posf - i0f;
        const int   i0   = (int)i0f;
        const int   i1   = i0 + 1;
        const float m0 = (i0 >= 0 && i0 < D_) ? 1.0f : 0.0f;
        const float m1 = (i1 >= 0 && i1 < D_) ? 1.0f : 0.0f;
        const int i0c = i0 < 0 ? 0 : (i0 > D_ - 1 ? D_ - 1 : i0);
        const int i1c = i1 < 0 ? 0 : (i1 > D_ - 1 ? D_ - 1 : i1);
        const float g0 = L[i0c * WT + wi];  // 65-stride diagonal: conflict-free
        const float g1 = L[i1c * WT + wi];
        dst[(size_t)k * HW] = g0 * ((1.0f - w1) * m0) + g1 * (w1 * m1);
      }
    }

    // (3) write-late: staged regs -> other buffer (free this whole iter)
    if (i + 1 < TPB) {
      float* Ln = lds[cur ^ 1];
#pragma unroll
      for (int j = 0; j < 4; ++j)
        *reinterpret_cast<float4*>(&Ln[(j * 32 + r0) * WT + c4]) = pf[j];
    }
    __syncthreads();
  }
}

extern "C" void kernel_launch(void* const* d_in, const int* in_sizes, int n_in,
                              void* d_out, int out_size, void* d_ws, size_t ws_size,
                              hipStream_t stream) {
  const float* corr    = (const float*)d_in[0];
  const int*   maxdisp = (const int*)d_in[1];
  const int*   is_ux   = (const int*)d_in[2];
  float*       out     = (float*)d_out;

  corr2cost_kernel<<<NBLK, NT, 0, stream>>>(corr, maxdisp, is_ux, out);
}

// Round 4
// 180.152 us; speedup vs baseline: 1.0054x; 1.0054x over previous
//
#include <hip/hip_runtime.h>

// Corr2Cost: out[b,c,k,h,w] = corr[b,c,d,h,w] at d = (is_ux?w:h)+k-m, zero
// outside [0,D). EXACTNESS: linspace(-m,m,2m+1) has step exactly 1.0 (2m/2m),
// endpoints integral -> pos is an exact-integer f32 -> w1 = pos-floor(pos) = 0
// -> reference reduces to g0*m0 bit-exactly. Single-tap gather is exact.
//
// R4: small tiles (w-half x 32 k-slots), 26 KB LDS, VGPR forced <=64 via
// __launch_bounds__(512,8) -> 4 independent blocks/CU x 8 waves = 32 waves/CU
// (R1-R3 never exceeded 16). Stage rows [dlo,dhi] coalesced, 1 conflict-free
// LDS read + 1 coalesced store per output. XCD-chunked swizzle keeps the 8
// sibling tiles (same bc,h -> overlapping input rows) on one XCD for L2 reuse.

#define B_ 8
#define C_ 2
#define D_ 128
#define H_ 96
#define W_ 128
#define WT 64
#define KC 32
#define NKT 4            // k-tiles of 32 slots: covers k 0..127 >= K=101
#define NT 512
#define RS 68            // LDS row stride: 68=4 mod 32 -> both phases conflict-free
#define MAXR 96          // max staged rows: (WT-1)+(KC-1)+1 = 95

__global__ __launch_bounds__(NT, 8) void corr2cost_kernel(
    const float* __restrict__ corr,
    const int* __restrict__ mp,
    const int* __restrict__ up,
    float* __restrict__ out) {
  __shared__ float lds[MAXR * RS];  // 26112 B

  // bijective XCD-chunk swizzle (gridDim.x % 8 == 0): consecutive logical
  // bids (sibling tiles) land on the same XCD, in dispatch order.
  const int cpx = gridDim.x >> 3;
  const int raw = blockIdx.x;
  const int bid = (raw & 7) * cpx + (raw >> 3);

  const int kt    = bid & (NKT - 1);
  const int whalf = (bid >> 2) & 1;
  const int sl    = bid >> 3;
  const int h     = sl % H_;
  const int bc    = sl / H_;

  const int t  = threadIdx.x;
  const int m  = *mp;
  const int ux = *up;
  const int K  = 2 * m + 1;
  const int HW = H_ * W_;
  const int w0 = whalf * WT;
  const int k0 = kt * KC;

  // d-rows this tile's (valid) taps can touch
  const int bmin = ux ? w0 : h;
  const int bmax = ux ? (w0 + WT - 1) : h;
  const int khi  = (k0 + KC - 1 < K - 1) ? (k0 + KC - 1) : (K - 1);
  const int dlo  = bmin + k0 - m;
  const int dhi  = bmax + khi - m;
  const int dlo_c = dlo > 0 ? dlo : 0;
  const int dhi_c = dhi < D_ - 1 ? dhi : D_ - 1;
  const int R = dhi_c - dlo_c + 1;  // may be <=0 (fully OOB tile: all zeros)

  // ---- stage rows [dlo_c, dhi_c] x [w0, w0+WT) into LDS (coalesced) ----
  const float* __restrict__ src =
      corr + (size_t)bc * D_ * HW + (size_t)h * W_ + w0;
  const int nf4 = R * (WT / 4);     // <= 96*16 = 1536 float4, <=3 per thread
  for (int i = t; i < nf4; i += NT) {
    const int r  = i >> 4;
    const int w4 = (i & 15) * 4;
    const float4 v =
        *reinterpret_cast<const float4*>(src + (size_t)(dlo_c + r) * HW + w4);
    *reinterpret_cast<float4*>(&lds[r * RS + w4]) = v;
  }
  __syncthreads();

  // ---- 4 outputs/thread: 1 LDS read + 1 coalesced 256B store each ----
  const int wi   = t & (WT - 1);
  const int kg   = t >> 6;          // wave id -> k wave-uniform (no divergence)
  const int base = ux ? (w0 + wi) : h;
  float* __restrict__ dst =
      out + (size_t)bc * K * HW + (size_t)h * W_ + w0 + wi;

#pragma unroll
  for (int j = 0; j < KC / 8; ++j) {
    const int k = k0 + kg + j * 8;
    const int d = base + k - m;
    const bool ok = (unsigned)d < (unsigned)D_;  // zero-pad mask (m0)
    int ld = d - dlo_c;                          // in [0,R) whenever ok
    ld = ld < 0 ? 0 : (ld > MAXR - 1 ? MAXR - 1 : ld);
    const float val = ok ? lds[ld * RS + wi] : 0.0f;
    if (k < K) dst[(size_t)k * HW] = val;        // uniform branch per wave
  }
}

extern "C" void kernel_launch(void* const* d_in, const int* in_sizes, int n_in,
                              void* d_out, int out_size, void* d_ws, size_t ws_size,
                              hipStream_t stream) {
  const float* corr    = (const float*)d_in[0];
  const int*   maxdisp = (const int*)d_in[1];
  const int*   is_ux   = (const int*)d_in[2];
  float*       out     = (float*)d_out;

  const int grid = B_ * C_ * H_ * 2 * NKT;  // 12288 blocks
  corr2cost_kernel<<<grid, NT, 0, stream>>>(corr, maxdisp, is_ux, out);
}

// Round 5
// 173.007 us; speedup vs baseline: 1.0469x; 1.0413x over previous
//
#include <hip/hip_runtime.h>

// Corr2Cost: out[b,c,k,h,w] = corr[b,c,d,h,w] at d = (is_ux?w:h)+k-m, zero
// outside [0,D). EXACT: linspace(-m,m,2m+1) step is exactly 1.0 -> w1 == 0
// -> single-tap gather is bit-exact vs the reference's 2-tap lerp.
//
// R5 theory: R1-R4 all sat at ~2.1 TB/s because each output was a serial
// ds_read(120cy) -> dependent store chain. Fix: 7 independent ds_reads
// batched before 7 stores (latency amortized 7x). No VGPR-forcing bound
// (R4's (512,8) produced VGPR=8 = fully serialized). 29 KB LDS -> 4 blocks
// x 8 waves = 32 waves/CU. Unpadded [row][64] tile: diagonal read stride
// 65 (odd) = conflict-free; float4 staging writes bank-balanced.

#define B_ 8
#define C_ 2
#define D_ 128
#define H_ 96
#define W_ 128
#define WT 64            // w-half per block
#define NT 512
#define MAXR 114         // max staged rows (m=50: R=114; ux=0: R<=101)

__global__ __launch_bounds__(NT) void corr2cost_kernel(
    const float* __restrict__ corr,
    const int* __restrict__ mp,
    const int* __restrict__ up,
    float* __restrict__ out) {
  __shared__ float lds[MAXR * WT];   // [row][w], row = d - dlo  (29184 B)

  const int t     = threadIdx.x;
  const int bid   = blockIdx.x;      // = (bc*H + h)*2 + whalf (natural order:
  const int whalf = bid & 1;         //   h-adjacent blocks write adjacent 256B
  const int sl    = bid >> 1;        //   segments -> time-local write merging)
  const int h     = sl % H_;
  const int bc    = sl / H_;

  const int m  = *mp;
  const int ux = *up;
  const int K  = 2 * m + 1;
  const int HW = H_ * W_;
  const int w0 = whalf * WT;

  // d-rows reachable by this block's valid taps
  const int bmin = ux ? w0 : h;
  const int bmax = ux ? (w0 + WT - 1) : h;
  int dlo = bmin - m;        if (dlo < 0) dlo = 0;
  int dhi = bmax + K - 1 - m; if (dhi > D_ - 1) dhi = D_ - 1;
  const int R = dhi - dlo + 1;        // <= MAXR for harness shapes

  // ---- stage rows [dlo,dhi] x [w0,w0+64) into LDS (coalesced float4) ----
  const float* __restrict__ src =
      corr + (size_t)bc * D_ * HW + (size_t)h * W_ + w0;
  const int nf4 = R * (WT / 4);       // <= 1824 float4, <= 4 per thread
  for (int i = t; i < nf4; i += NT) {
    const int r  = i >> 4;
    const int c4 = (i & 15) * 4;
    *reinterpret_cast<float4*>(&lds[r * WT + c4]) =
        *reinterpret_cast<const float4*>(src + (size_t)(dlo + r) * HW + c4);
  }
  __syncthreads();

  // ---- compute: each thread owns one w, k = kseg + 8*kk (kk = 0..12) ----
  // 7-deep batches of INDEPENDENT ds_reads, then the 7 stores.
  const int w    = t & (WT - 1);      // lane -> contiguous 256B store segments
  const int kseg = t >> 6;            // wave id: k wave-uniform
  const int base = ux ? (w0 + w) : h;
  float* __restrict__ dst =
      out + (size_t)bc * K * HW + (size_t)h * W_ + w0 + w;

  const int NB = (K + 7) >> 3;        // 13 k's per thread (K=101)
  for (int kb = 0; kb < NB; kb += 7) {
    float v[7];
#pragma unroll
    for (int j = 0; j < 7; ++j) {     // 7 independent LDS reads, no chains
      const int k  = kseg + (kb + j) * 8;
      const int d  = base + k - m;
      const bool ok = (unsigned)d < (unsigned)D_;
      int rr = d - dlo;
      rr = rr < 0 ? 0 : (rr > MAXR - 1 ? MAXR - 1 : rr);
      v[j] = ok ? lds[rr * WT + w] : 0.0f;   // stride-65 diagonal: conflict-free
    }
#pragma unroll
    for (int j = 0; j < 7; ++j) {     // then 7 fire-and-forget stores
      const int k = kseg + (kb + j) * 8;
      if (k < K) dst[(size_t)k * HW] = v[j];  // wave-uniform branch
    }
  }
}

extern "C" void kernel_launch(void* const* d_in, const int* in_sizes, int n_in,
                              void* d_out, int out_size, void* d_ws, size_t ws_size,
                              hipStream_t stream) {
  const float* corr    = (const float*)d_in[0];
  const int*   maxdisp = (const int*)d_in[1];
  const int*   is_ux   = (const int*)d_in[2];
  float*       out     = (float*)d_out;

  const int grid = B_ * C_ * H_ * 2;  // 3072 blocks, one per (b,c,h,w-half)
  corr2cost_kernel<<<grid, NT, 0, stream>>>(corr, maxdisp, is_ux, out);
}